// Round 11
// baseline (345.916 us; speedup 1.0000x reference)
//
#include <hip/hip_runtime.h>

typedef unsigned short u16;
typedef unsigned int   u32;

using bf16x8 = __attribute__((ext_vector_type(8))) __bf16;
using f32x4  = __attribute__((ext_vector_type(4))) float;

__device__ __forceinline__ float bf2f(u16 h){ return __uint_as_float(((u32)h) << 16); }
__device__ __forceinline__ u16 f2bf(float f){
    u32 u = __float_as_uint(f);
    u32 r = u + 0x7FFFu + ((u >> 16) & 1u);   // round-to-nearest-even
    return (u16)(r >> 16);
}

// async global->LDS, 16B per lane; LDS dest = wave-uniform base + lane*16.
__device__ __forceinline__ void async16(const void* g, void* l){
    __builtin_amdgcn_global_load_lds(
        (const __attribute__((address_space(1))) unsigned int*)g,
        (__attribute__((address_space(3))) unsigned int*)l, 16, 0, 0);
}
__device__ __forceinline__ bf16x8 cvt8(uint4 v){
    union { uint4 u; bf16x8 b; } c; c.u = v; return c.b;
}

// ---------------------------------------------------------------------------
// PREP_ALL v16: one launch = v15's prep tiles + bias (ids 0..3475, local
// isbf probe per block — mega-validated) + grouping (id 3476, writes
// slot_of_node AND node_of_slot) + flags probe (id 3477) + 64 sums-zero
// blocks (ids 3478..3541). All families have disjoint outputs; trans /
// fused / l2 consume them in LATER launches (no intra-kernel deps).
// ---------------------------------------------------------------------------
__global__ __launch_bounds__(256)
void prep_all(const void* x, const void* masks, const int* labels,
    const void* w10, const void* w11, const void* w12,
    const void* w20, const void* w21, const void* w22,
    const void* bb10, const void* bb11, const void* bb12,
    const void* bb20, const void* bb21, const void* bb22,
    u16* feat, u16* B1T, u16* W2T, float* b1f, float* b2f,
    int* flags, int* slot_of_node, int* node_of_slot, int* ovf_flag,
    float* zbuf, unsigned int zf4)
{
    constexpr int NN_ = 300;
    constexpr int NFEAT = 626 * 4;            // 2504
    constexpr int NB1 = NFEAT + 192;          // 2696
    constexpr int NW2 = NB1 + 768;            // 3464
    constexpr int NTILE = NW2 + 12;           // 3476 (incl. bias blocks)
    constexpr int GROUP_ID = NTILE;           // 3476
    constexpr int PROBE_ID = NTILE + 1;       // 3477
    constexpr int ZERO_BASE = NTILE + 2;      // 3478 (+64 blocks)

    __shared__ u16 tile[64 * 68];             // 8704 B transpose tile
    __shared__ int lab[NN_];
    __shared__ short rnk[NN_];
    __shared__ unsigned char sp[NN_];
    __shared__ int s_info;

    const int id = blockIdx.x;
    const int tid = threadIdx.x;

    // ---- sums|sumsOvf|counts zero (grid-stride float4) ----
    if (id >= ZERO_BASE){
        const unsigned int nthr = 64u * 256u;
        unsigned int i = (id - ZERO_BASE) * 256 + tid;
        float4 z = make_float4(0.f, 0.f, 0.f, 0.f);
        for (; i < zf4; i += nthr)
            reinterpret_cast<float4*>(zbuf)[i] = z;
        return;
    }

    // ---- flags probe (consumed by trans + l2 epilogue, later launches) ----
    if (id == PROBE_ID){
        if (tid < 64){
            const u16* hx = (const u16*)x;
            int e0 = (hx[tid] >> 7) & 0xFF;
            int e1 = (hx[tid + 64] >> 7) & 0xFF;
            unsigned long long b0 = __ballot(e0 >= 100 && e0 <= 140);
            unsigned long long b1 = __ballot(e1 >= 100 && e1 <= 140);
            int cnt = __popcll(b0) + __popcll(b1);
            const u32* w  = (const u32*)masks;
            const u16* hm = (const u16*)masks;
            u32 v = w[tid];
            unsigned long long i32bad = __ballot(v > 1u);
            unsigned long long f32bad = __ballot(v != 0u && v != 0x3F800000u);
            u16 h0 = hm[tid], h1 = hm[tid + 64];
            unsigned long long bfbad =
                __ballot((h0 != 0 && h0 != 0x3F80) || (h1 != 0 && h1 != 0x3F80));
            if (tid == 0){
                flags[0] = (cnt >= 100) ? 1 : 0;
                int md = 0;
                if (!i32bad) md = 1; else if (!f32bad) md = 3; else if (!bfbad) md = 2;
                flags[1] = md;
            }
        }
        return;
    }

    // ---- label grouping (mega-validated; now ALSO writes slot_of_node) ----
    if (id == GROUP_ID){
        for (int idx = tid; idx < 512; idx += 256) node_of_slot[idx] = -1;
        for (int n = tid; n < NN_; n += 256) lab[n] = labels[n];
        __syncthreads();
        for (int n = tid; n < NN_; n += 256){
            int k = lab[n], r = 0;
            for (int j = 0; j < n; j++) r += (lab[j] == k);
            rnk[n] = (short)r; sp[n] = (r >= 128) ? 1 : 0;
        }
        __syncthreads();
        for (int n = tid; n < NN_; n += 256){
            int r = rnk[n]; int slot;
            if (r < 128) slot = lab[n] * 128 + r;
            else { int so = 0; for (int j = 0; j < n; j++) so += sp[j]; slot = 384 + so; }
            slot_of_node[n] = slot;
            node_of_slot[slot] = n;
        }
        if (tid == 0){
            int tot = 0;
            for (int j = 0; j < NN_; j++) tot += sp[j];
            *ovf_flag = tot;
        }
        return;
    }

    // ---- prep tiles + bias: local isbf probe (mega-validated pattern) ----
    if (tid < 64){
        const u16* hx = (const u16*)x;
        int e0 = (hx[tid] >> 7) & 0xFF;
        int e1 = (hx[tid + 64] >> 7) & 0xFF;
        unsigned long long b0 = __ballot(e0 >= 100 && e0 <= 140);
        unsigned long long b1 = __ballot(e1 >= 100 && e1 <= 140);
        if (tid == 0) s_info = (__popcll(b0) + __popcll(b1) >= 100) ? 1 : 0;
    }
    __syncthreads();
    const bool isbf = (s_info != 0);

    const void* src; u16* d; int J, ldd, i0, j0;
    if (id < NFEAT){
        int pblk = id >> 2, cblk = id & 3;
        src = x; d = feat; J = 40000; ldd = 256;
        j0 = pblk * 64; i0 = cblk * 64;
    } else if (id < NB1){
        int idx = id - NFEAT;
        int z = idx >> 6, r2 = idx & 63;
        src = (z == 0) ? w10 : (z == 1) ? w11 : w12;
        d = B1T + (size_t)z * 1024 * 256;
        J = 1024; ldd = 256;
        j0 = (r2 & 15) * 64; i0 = (r2 >> 4) * 64;
    } else if (id < NW2){
        int idx = id - NB1;
        int z = idx >> 8, r2 = idx & 255;
        src = (z == 0) ? w20 : (z == 1) ? w21 : w22;
        d = W2T + (size_t)z * 1024 * 1024;
        J = 1024; ldd = 1024;
        j0 = (r2 & 15) * 64; i0 = (r2 >> 4) * 64;
    } else {
        int idx = (id - NW2) * 256 + tid;
        if (idx < 3072){
            int k = idx >> 10, r2 = idx & 1023;
            const void* p1 = (k == 0) ? bb10 : (k == 1) ? bb11 : bb12;
            const void* p2 = (k == 0) ? bb20 : (k == 1) ? bb21 : bb22;
            b1f[idx] = isbf ? bf2f(((const u16*)p1)[r2]) : ((const float*)p1)[r2];
            b2f[idx] = isbf ? bf2f(((const u16*)p2)[r2]) : ((const float*)p2)[r2];
        }
        return;
    }

    const int wave = tid >> 6, lane = tid & 63;
    const int rr = wave * 4 + (lane >> 4);    // row within pass-group of 16
    const int cc = (lane & 15) * 4;           // col, 4-wide per lane

    // ---- read phase: src rows -> bf16 LDS tile (4 passes x 16 rows) ----
    if (j0 >= J){
        #pragma unroll
        for (int pass = 0; pass < 4; pass++){
            const int r = pass * 16 + rr;
            union { u16 h[4]; uint2 v; } pk;
            pk.h[0] = 0; pk.h[1] = 0; pk.h[2] = 0; pk.h[3] = 0;
            *reinterpret_cast<uint2*>(&tile[r * 68 + cc]) = pk.v;
        }
    } else if (isbf){
        const u16* sh = (const u16*)src;
        #pragma unroll
        for (int pass = 0; pass < 4; pass++){
            const int r = pass * 16 + rr;
            const size_t ix = (size_t)(i0 + r) * J + (j0 + cc);
            ushort4 v = *reinterpret_cast<const ushort4*>(&sh[ix]);
            union { u16 h[4]; uint2 u; } pk;
            pk.h[0] = v.x; pk.h[1] = v.y; pk.h[2] = v.z; pk.h[3] = v.w;
            *reinterpret_cast<uint2*>(&tile[r * 68 + cc]) = pk.u;
        }
    } else {
        const float* sf = (const float*)src;
        #pragma unroll
        for (int pass = 0; pass < 4; pass++){
            const int r = pass * 16 + rr;
            const size_t ix = (size_t)(i0 + r) * J + (j0 + cc);
            float4 v = *reinterpret_cast<const float4*>(&sf[ix]);
            union { u16 h[4]; uint2 u; } pk;
            pk.h[0] = f2bf(v.x); pk.h[1] = f2bf(v.y);
            pk.h[2] = f2bf(v.z); pk.h[3] = f2bf(v.w);
            *reinterpret_cast<uint2*>(&tile[r * 68 + cc]) = pk.u;
        }
    }
    __syncthreads();

    // ---- write phase: column gather -> 16B contiguous stores ----
    #pragma unroll
    for (int pass = 0; pass < 2; pass++){
        const int s = pass * 256 + tid;       // [0, 512)
        const int p = s & 63;                 // tile col = dest row offset
        const int chunk = s >> 6;             // [0, 8)
        union { u16 h[8]; uint4 v; } pk;
        #pragma unroll
        for (int k = 0; k < 8; k++)
            pk.h[k] = tile[(chunk * 8 + k) * 68 + p];
        *reinterpret_cast<uint4*>(
            &d[(size_t)(j0 + p) * ldd + i0 + chunk * 8]) = pk.v;
    }
}

// ---------------------------------------------------------------------------
// masks [P][NN] -> mfT[slot][p] bf16 {0,1} (rows permuted), fused popcount.
// (FROZEN — proven R5/R9.) mfT NOT pre-zeroed: empty-slot rows carry
// garbage by design; node_of_slot gate in l2 discards them.
// ---------------------------------------------------------------------------
__global__ void trans_mask_count(const void* src, u16* dst,
                                 const int* slot_of_node, float* counts,
                                 const int* flags)
{
    constexpr int NN_ = 300, P_ = 40000, LDP = 40064;
    __shared__ u16 tile[128][33];    // [p_in][n_in]
    __shared__ int slt[32];
    const int p0 = blockIdx.x * 128, n0 = blockIdx.y * 32;
    const int tid = threadIdx.x;
    const int md = flags[1];
    if (tid < 32) slt[tid] = (n0 + tid < NN_) ? slot_of_node[n0 + tid] : -1;

    if (md == 0){
        const unsigned char* s8 = (const unsigned char*)src;
        const int tx = tid & 7, ty = tid >> 3;
        #pragma unroll
        for (int rep = 0; rep < 4; rep++){
            const int p = p0 + rep * 32 + ty;
            const int nb = n0 + tx * 4;
            u32 w = 0;
            if (p < P_){
                if (nb + 3 < NN_)
                    w = *(const u32*)(s8 + (size_t)p * NN_ + nb);
                else {
                    for (int b = 0; b < 4; b++)
                        if (nb + b < NN_)
                            w |= (u32)s8[(size_t)p * NN_ + nb + b] << (8 * b);
                }
            }
            #pragma unroll
            for (int b = 0; b < 4; b++)
                tile[rep * 32 + ty][tx * 4 + b] =
                    ((w >> (8 * b)) & 0xFFu) ? (u16)0x3F80 : (u16)0;
        }
    } else {
        #pragma unroll
        for (int it = 0; it < 16; it++){
            const int e = tid + it * 256;
            const int n_in = e & 31, p_in = e >> 5;
            const int p = p0 + p_in, n = n0 + n_in;
            u16 v = 0;
            if (p < P_ && n < NN_){
                size_t idx = (size_t)p * NN_ + n;
                bool on;
                if (md == 1)      on = ((const int*)src)[idx] != 0;
                else if (md == 2) on = ((const u16*)src)[idx] != 0;
                else              on = ((const float*)src)[idx] != 0.f;
                v = on ? (u16)0x3F80 : (u16)0;
            }
            tile[p_in][n_in] = v;
        }
    }
    __syncthreads();

    #pragma unroll
    for (int half = 0; half < 2; half++){
        const int row = tid >> 3;
        const int pos = (tid & 7) + half * 8;
        const int slot = slt[row];
        if (slot >= 0){
            union { u16 h[8]; uint4 v; } tmp;
            #pragma unroll
            for (int j = 0; j < 8; j++) tmp.h[j] = tile[pos * 8 + j][row];
            *reinterpret_cast<uint4*>(&dst[(size_t)slot * LDP + p0 + pos * 8]) = tmp.v;
        }
    }
    if (tid < 32){
        const int slot = slt[tid];
        if (slot >= 0){
            int c = 0;
            for (int p = 0; p < 128; p++) c += (tile[p][tid] != 0);
            if (c > 0) atomicAdd(&counts[slot], (float)c);
        }
    }
}

// ---------------------------------------------------------------------------
// FUSED L1 + mask-sum v16 = v12 body (FROZEN) with MAP0 + overflow merged
// into ONE launch (they are mutually independent: both read prep/trans
// outputs only; disjoint sums3/sumsOvf writes). ids 0..511 = MAP0 grid
// verbatim; ids 512..703 = overflow (24 x 8), gated on skipf. Hot loop is
// byte-identical to v12; only setup/epilogue branch on isOvf.
// ---------------------------------------------------------------------------
__global__ __launch_bounds__(256, 2)
void fused_l1_mask_all(const u16* __restrict__ B1T, const u16* __restrict__ feat,
                       const u16* __restrict__ mfT, const float* __restrict__ b1f,
                       float* __restrict__ sums3, float* __restrict__ sumsOvf,
                       const int* __restrict__ skipf)
{
    constexpr int PPAD = 40064;
    __shared__ __align__(16) u16 As[32768];   // [8 kt][128 m][32 c]  64 KB
    __shared__ __align__(16) u16 Hs[8192];    // [4 pc][64 mh][32 p]  16 KB

    const int gid = blockIdx.x;
    const bool isOvf = (gid >= 512);
    if (isOvf && *skipf == 0) return;

    int bx, ts, te, srow;
    float* __restrict__ sums;
    if (!isOvf){
        // id = 64g + 8s + r; combo = 8g + r = branch*21 + y; the 8
        // m-subtiles of a (branch, y) share id%8 -> one XCD.
        const int r = gid & 7, s = (gid >> 3) & 7, g = gid >> 6;
        const int combo = g * 8 + r;
        if (combo >= 63) return;              // 8 idle ids
        const int branch = combo / 21, y = combo % 21;
        bx = branch * 8 + s;
        ts = y * 15; te = ts + 15; if (te > 313) te = 313;
        srow = (bx >> 3) * 128;
        sums = sums3;
    } else {
        const int id2 = gid - 512;            // [0, 192)
        bx = id2 % 24;                        // m over all 3072
        const int yb = id2 / 24;              // [0, 8)
        ts = yb * 40; te = ts + 40; if (te > 313) te = 313;
        if (ts >= te) return;
        srow = 384;
        sums = sumsOvf;
    }
    const int m0 = bx * 128;

    const int tid = threadIdx.x;
    const int wave = tid >> 6, lane = tid & 63;
    const int t = lane & 15, q = lane >> 4;

    {
        const int cr = lane >> 2, cp = lane & 3;
        const int ca = wave * 2, cb = wave * 2 + 1;
        const u16* gA0 = B1T + (size_t)(m0 + ca * 16 + cr) * 256 + cp * 8;
        const u16* gA1 = B1T + (size_t)(m0 + cb * 16 + cr) * 256 + cp * 8;
        #pragma unroll
        for (int kt = 0; kt < 8; kt++){
            async16(gA0 + kt * 32, &As[kt * 4096 + ca * 512]);
            async16(gA1 + kt * 32, &As[kt * 4096 + cb * 512]);
        }
    }

    const u16* mrow = mfT + (size_t)(srow + wave * 32 + t) * PPAD + q * 8;
    const u16* gF   = feat + (size_t)(wave * 32 + t) * 256 + q * 8;
    const float4* bsrc = reinterpret_cast<const float4*>(b1f + m0) + q;

    f32x4 acc2[2][8];
    #pragma unroll
    for (int a = 0; a < 2; a++)
        #pragma unroll
        for (int b = 0; b < 8; b++)
            #pragma unroll
            for (int e = 0; e < 4; e++) acc2[a][b][e] = 0.f;

    uint4 bgv[2];
    #pragma unroll
    for (int ni = 0; ni < 2; ni++)
        bgv[ni] = *reinterpret_cast<const uint4*>(
            gF + (size_t)(ts * 128 + ni * 16) * 256);

    __syncthreads();   // As resident (+ bgv drained)

#define HWRITE(MOFF) do{                                                      \
    _Pragma("unroll")                                                         \
    for (int mi = 0; mi < 4; mi++){                                           \
        _Pragma("unroll")                                                     \
        for (int i = 0; i < 4; i++){                                          \
            const int m_l = mi * 16 + q * 4 + i;                              \
            _Pragma("unroll")                                                 \
            for (int ni = 0; ni < 2; ni++){                                   \
                const int pin = ni * 16 + t;                                  \
                float v = acc1[(MOFF) + mi][ni][i];                           \
                v = (v > 0.f) ? v : 0.f;                                      \
                const int cg = (pin >> 3) ^ q;                                \
                Hs[wave * 2048 + m_l * 32 + cg * 8 + (pin & 7)] = f2bf(v);    \
            }                                                                 \
        }                                                                     \
    }                                                                         \
}while(0)

#define S2HALF(NOFF) do{                                                      \
    _Pragma("unroll")                                                         \
    for (int lc = 0; lc < 4; lc++){                                           \
        const int hq_ = (q ^ ((t >> 2) & 3)) * 8;                             \
        bf16x8 hb0_ = *reinterpret_cast<const bf16x8*>(                       \
            &Hs[lc * 2048 + (0 * 16 + t) * 32 + hq_]);                        \
        bf16x8 hb1_ = *reinterpret_cast<const bf16x8*>(                       \
            &Hs[lc * 2048 + (1 * 16 + t) * 32 + hq_]);                        \
        bf16x8 hb2_ = *reinterpret_cast<const bf16x8*>(                       \
            &Hs[lc * 2048 + (2 * 16 + t) * 32 + hq_]);                        \
        bf16x8 hb3_ = *reinterpret_cast<const bf16x8*>(                       \
            &Hs[lc * 2048 + (3 * 16 + t) * 32 + hq_]);                        \
        __builtin_amdgcn_s_setprio(1);                                        \
        acc2[0][(NOFF)+0] = __builtin_amdgcn_mfma_f32_16x16x32_bf16(          \
            cvt8(mk[lc][0]), hb0_, acc2[0][(NOFF)+0], 0, 0, 0);               \
        acc2[0][(NOFF)+1] = __builtin_amdgcn_mfma_f32_16x16x32_bf16(          \
            cvt8(mk[lc][0]), hb1_, acc2[0][(NOFF)+1], 0, 0, 0);               \
        acc2[0][(NOFF)+2] = __builtin_amdgcn_mfma_f32_16x16x32_bf16(          \
            cvt8(mk[lc][0]), hb2_, acc2[0][(NOFF)+2], 0, 0, 0);               \
        acc2[0][(NOFF)+3] = __builtin_amdgcn_mfma_f32_16x16x32_bf16(          \
            cvt8(mk[lc][0]), hb3_, acc2[0][(NOFF)+3], 0, 0, 0);               \
        acc2[1][(NOFF)+0] = __builtin_amdgcn_mfma_f32_16x16x32_bf16(          \
            cvt8(mk[lc][1]), hb0_, acc2[1][(NOFF)+0], 0, 0, 0);               \
        acc2[1][(NOFF)+1] = __builtin_amdgcn_mfma_f32_16x16x32_bf16(          \
            cvt8(mk[lc][1]), hb1_, acc2[1][(NOFF)+1], 0, 0, 0);               \
        acc2[1][(NOFF)+2] = __builtin_amdgcn_mfma_f32_16x16x32_bf16(          \
            cvt8(mk[lc][1]), hb2_, acc2[1][(NOFF)+2], 0, 0, 0);               \
        acc2[1][(NOFF)+3] = __builtin_amdgcn_mfma_f32_16x16x32_bf16(          \
            cvt8(mk[lc][1]), hb3_, acc2[1][(NOFF)+3], 0, 0, 0);               \
        __builtin_amdgcn_s_setprio(0);                                        \
    }                                                                         \
}while(0)

    for (int pt = ts; pt < te; ++pt){
        const int p0 = pt * 128;

        f32x4 acc1[8][2];
        #pragma unroll
        for (int mi = 0; mi < 8; mi++){
            float4 bb = bsrc[mi * 4];
            #pragma unroll
            for (int ni = 0; ni < 2; ni++){
                acc1[mi][ni][0] = bb.x; acc1[mi][ni][1] = bb.y;
                acc1[mi][ni][2] = bb.z; acc1[mi][ni][3] = bb.w;
            }
        }

        uint4 mk[4][2];   // mask frags [lc][si], loaded once, used twice

        #pragma unroll
        for (int kt = 0; kt < 8; ++kt){
            bf16x8 af[8];
            #pragma unroll
            for (int mi = 0; mi < 8; mi++)
                af[mi] = *reinterpret_cast<const bf16x8*>(
                    &As[kt * 4096 + (mi * 16 + t) * 32 + q * 8]);
            uint4 nxt[2];
            if (kt < 7){
                #pragma unroll
                for (int ni = 0; ni < 2; ni++)
                    nxt[ni] = *reinterpret_cast<const uint4*>(
                        gF + (size_t)(p0 + ni * 16) * 256 + (kt + 1) * 32);
            }
            if (kt == 6){
                #pragma unroll
                for (int si = 0; si < 2; si++){
                    mk[0][si] = *reinterpret_cast<const uint4*>(
                        mrow + (size_t)(si * 16) * PPAD + p0 + 0 * 32);
                    mk[1][si] = *reinterpret_cast<const uint4*>(
                        mrow + (size_t)(si * 16) * PPAD + p0 + 1 * 32);
                }
            } else if (kt == 7){
                #pragma unroll
                for (int si = 0; si < 2; si++){
                    mk[2][si] = *reinterpret_cast<const uint4*>(
                        mrow + (size_t)(si * 16) * PPAD + p0 + 2 * 32);
                    mk[3][si] = *reinterpret_cast<const uint4*>(
                        mrow + (size_t)(si * 16) * PPAD + p0 + 3 * 32);
                }
            }
            __builtin_amdgcn_s_setprio(1);
            #pragma unroll
            for (int mi = 0; mi < 8; mi++)
                #pragma unroll
                for (int ni = 0; ni < 2; ni++)
                    acc1[mi][ni] = __builtin_amdgcn_mfma_f32_16x16x32_bf16(
                        af[mi], cvt8(bgv[ni]), acc1[mi][ni], 0, 0, 0);
            __builtin_amdgcn_s_setprio(0);
            if (kt < 7){ bgv[0] = nxt[0]; bgv[1] = nxt[1]; }
        }

        HWRITE(0);
        __syncthreads();   // Hs half-0 ready; mk drained (vmcnt 0)

        S2HALF(0);
        __syncthreads();   // protect Hs before half-1 writes

        HWRITE(4);
        if (pt + 1 < te){
            #pragma unroll
            for (int ni = 0; ni < 2; ni++)
                bgv[ni] = *reinterpret_cast<const uint4*>(
                    gF + (size_t)((pt + 1) * 128 + ni * 16) * 256);
        }
        __syncthreads();   // Hs half-1 ready

        S2HALF(4);
        __syncthreads();   // protect Hs before next p-tile's writes
    }
#undef HWRITE
#undef S2HALF

    #pragma unroll
    for (int si = 0; si < 2; si++){
        #pragma unroll
        for (int i = 0; i < 4; i++){
            const int slot_l = wave * 32 + si * 16 + q * 4 + i;
            #pragma unroll
            for (int ni = 0; ni < 8; ni++){
                const int m_l = ni * 16 + t;
                const float v = acc2[si][ni][i];
                if (!isOvf)
                    atomicAdd(sums + (size_t)((bx >> 3) * 128 + slot_l) * 1024
                                   + (bx & 7) * 128 + m_l, v);
                else
                    atomicAdd(sums + (size_t)slot_l * 3072 + bx * 128 + m_l, v);
            }
        }
    }
}

// ---------------------------------------------------------------------------
// L2 GEMM (FROZEN): double-buffered, one barrier per K-step; A scaled by
// 1/count + bf16-converted during staging; epilogue bias + scatter.
// ---------------------------------------------------------------------------
__global__ __launch_bounds__(256)
void l2_gemm(const float* __restrict__ sums3, const float* __restrict__ sumsOvf,
             const float* __restrict__ counts, const u16* __restrict__ W2T,
             const float* __restrict__ b2f, const int* __restrict__ node_of_slot,
             const int* __restrict__ labels, const int* __restrict__ ovfflag,
             void* __restrict__ dout, const int* __restrict__ flags)
{
    const int z = blockIdx.z;
    const int k = (z >= 3) ? z - 3 : z;
    if (z >= 3 && *ovfflag == 0) return;
    const int n0 = blockIdx.x * 128;

    const float* Arow; int astride, slotbase;
    if (z < 3){ Arow = sums3 + (size_t)z * 128 * 1024; astride = 1024; slotbase = z * 128; }
    else      { Arow = sumsOvf + (size_t)k * 1024;     astride = 3072; slotbase = 384; }

    __shared__ __align__(16) u16 As[2][4096];
    __shared__ __align__(16) u16 Bs[2][4096];
    __shared__ float invc[128];

    const int tid  = threadIdx.x;
    const int wave = tid >> 6, lane = tid & 63;
    const int wr = wave >> 1, wc = wave & 1;
    const int t = lane & 15, q = lane >> 4;

    if (tid < 128){
        float c = counts[slotbase + tid];
        invc[tid] = (c > 0.f) ? 1.f / c : 0.f;
    }
    __syncthreads();

    const u16* Bsrc = W2T + (size_t)k * 1024 * 1024;
    const int cr = lane >> 2, cp = lane & 3;
    const int ca = wave * 2, cb = wave * 2 + 1;
    const u16* gB0 = Bsrc + (size_t)(n0 + ca * 16 + cr) * 1024 + cp * 8;
    const u16* gB1 = Bsrc + (size_t)(n0 + cb * 16 + cr) * 1024 + cp * 8;

    const int srow0 = tid >> 2, sq0 = tid & 3;     // A-staging row/quarter
    const int srow1 = srow0 + 64;

    float4 sv[2][2];

#define L2_LOAD(ktv) do{ \
    const float4* _p0 = reinterpret_cast<const float4*>( \
        Arow + (size_t)srow0 * astride + (ktv) * 32 + sq0 * 8); \
    const float4* _p1 = reinterpret_cast<const float4*>( \
        Arow + (size_t)srow1 * astride + (ktv) * 32 + sq0 * 8); \
    sv[0][0] = _p0[0]; sv[0][1] = _p0[1]; \
    sv[1][0] = _p1[0]; sv[1][1] = _p1[1]; }while(0)

#define L2_WRITE(bufv) do{ \
    _Pragma("unroll") \
    for (int rep = 0; rep < 2; rep++){ \
        const int row = (rep == 0) ? srow0 : srow1; \
        const float s = invc[row]; \
        float4 v0 = sv[rep][0], v1 = sv[rep][1]; \
        union { u16 h[8]; uint4 v; } pk; \
        pk.h[0] = f2bf(v0.x * s); pk.h[1] = f2bf(v0.y * s); \
        pk.h[2] = f2bf(v0.z * s); pk.h[3] = f2bf(v0.w * s); \
        pk.h[4] = f2bf(v1.x * s); pk.h[5] = f2bf(v1.y * s); \
        pk.h[6] = f2bf(v1.z * s); pk.h[7] = f2bf(v1.w * s); \
        *reinterpret_cast<uint4*>(&As[bufv][row * 32 + sq0 * 8]) = pk.v; \
    } }while(0)

    // prologue: stage kt=0 into buffer 0
    L2_LOAD(0);
    L2_WRITE(0);
    async16(gB0, &Bs[0][ca * 512]);
    async16(gB1, &Bs[0][cb * 512]);
    __syncthreads();

    f32x4 acc[4][4];
    #pragma unroll
    for (int a = 0; a < 4; a++)
        #pragma unroll
        for (int b = 0; b < 4; b++)
            #pragma unroll
            for (int e = 0; e < 4; e++) acc[a][b][e] = 0.f;

    int buf = 0;
    for (int kt = 0; kt < 32; ++kt){
        if (kt < 31) L2_LOAD(kt + 1);                     // global A, kt+1
        bf16x8 af[4], bg[4];
        #pragma unroll
        for (int mi = 0; mi < 4; mi++)
            af[mi] = *reinterpret_cast<const bf16x8*>(
                &As[buf][(wr * 64 + mi * 16 + t) * 32 + q * 8]);
        #pragma unroll
        for (int ni = 0; ni < 4; ni++)
            bg[ni] = *reinterpret_cast<const bf16x8*>(
                &Bs[buf][(wc * 64 + ni * 16 + t) * 32 + q * 8]);
        if (kt < 31){
            async16(gB0 + (kt + 1) * 32, &Bs[buf ^ 1][ca * 512]);
            async16(gB1 + (kt + 1) * 32, &Bs[buf ^ 1][cb * 512]);
        }
        __builtin_amdgcn_s_setprio(1);
        #pragma unroll
        for (int mi = 0; mi < 4; mi++)
            #pragma unroll
            for (int ni = 0; ni < 4; ni++)
                acc[mi][ni] = __builtin_amdgcn_mfma_f32_16x16x32_bf16(
                    af[mi], bg[ni], acc[mi][ni], 0, 0, 0);
        __builtin_amdgcn_s_setprio(0);
        if (kt < 31) L2_WRITE(buf ^ 1);                   // LDS A, kt+1
        __syncthreads();
        buf ^= 1;
    }
#undef L2_LOAD
#undef L2_WRITE

    const bool outbf = (flags[0] != 0);
    #pragma unroll
    for (int mi = 0; mi < 4; mi++){
        #pragma unroll
        for (int i = 0; i < 4; i++){
            int m_l = wr * 64 + mi * 16 + q * 4 + i;
            int node = node_of_slot[slotbase + m_l];
            bool ok = (node >= 0) && (z < 3 || labels[node] == k);
            if (!ok) continue;
            #pragma unroll
            for (int ni = 0; ni < 4; ni++){
                int n = n0 + wc * 64 + ni * 16 + t;
                float v = acc[mi][ni][i] + b2f[k * 1024 + n];
                size_t oi = (size_t)node * 1024 + n;
                if (outbf) ((u16*)dout)[oi] = f2bf(v);
                else       ((float*)dout)[oi] = v;
            }
        }
    }
}

// ---------------------------------------------------------------------------
extern "C" void kernel_launch(void* const* d_in, const int* in_sizes, int n_in,
                              void* d_out, int out_size, void* d_ws, size_t ws_size,
                              hipStream_t stream)
{
    constexpr int C = 256, R = 1024;
    constexpr int PPAD = 40064;          // 313 * 128
    constexpr int M1 = 3 * R;            // 3072 L1 rows (branch-major)
    constexpr int SLOTS = 512;           // 3*128 grouped + 128 overflow

    const void* x      = d_in[0];
    const void* masks  = d_in[1];
    const int*  labels = (const int*)d_in[2];
    (void)in_sizes; (void)n_in; (void)out_size; (void)ws_size;

    char* ws = (char*)d_ws;
    size_t off = 0;
    auto alloc = [&](size_t b)->size_t {
        size_t o = off; off += (b + 255) & ~(size_t)255; return o;
    };

    int*   flags   = (int*)  (ws + alloc(256));
    int*   slotmap = (int*)  (ws + alloc(384 * 4));
    int*   nodemap = (int*)  (ws + alloc(512 * 4));
    int*   ovfflag = (int*)  (ws + alloc(256));
    u16*   feat    = (u16*)  (ws + alloc((size_t)PPAD * C * 2));    // [p][c]
    u16*   B1T     = (u16*)  (ws + alloc((size_t)M1 * C * 2));      // [m][c]
    float* b1f     = (float*)(ws + alloc((size_t)M1 * 4));
    float* b2f     = (float*)(ws + alloc((size_t)M1 * 4));
    u16*   mfT     = (u16*)  (ws + alloc((size_t)SLOTS * PPAD * 2));// [slot][p]
    // contiguous zero region: sums3 | sumsOvf | counts
    float* sums3   = (float*)(ws + alloc((size_t)384 * 1024 * 4));
    float* sumsOvf = (float*)(ws + alloc((size_t)128 * M1 * 4));
    float* counts  = (float*)(ws + alloc((size_t)SLOTS * 4));
    u16*   W2T     = (u16*)  (ws + alloc((size_t)3 * R * R * 2));

    // sums|sumsOvf|counts zero region, in float4 units
    const unsigned int zf4 = (384u * 1024u + 128u * 3072u + 512u) / 4u;

    // ONE prep launch: tiles+bias (local isbf) | grouping | probe | zero
    prep_all<<<3476 + 2 + 64, 256, 0, stream>>>(
        x, masks, labels,
        d_in[3], d_in[7], d_in[11],              // W1
        d_in[5], d_in[9], d_in[13],              // W2
        d_in[4], d_in[8], d_in[12],              // b1
        d_in[6], d_in[10], d_in[14],             // b2
        feat, B1T, W2T, b1f, b2f,
        flags, slotmap, nodemap, ovfflag, sums3, zf4);

    trans_mask_count<<<dim3(PPAD / 128, 384 / 32), 256, 0, stream>>>(
        masks, mfT, slotmap, counts, flags);

    // fused L1 + mask-sum, MAP0 (512 ids) + overflow (192 ids) in ONE launch
    fused_l1_mask_all<<<512 + 192, 256, 0, stream>>>(
        B1T, feat, mfT, b1f, sums3, sumsOvf, ovfflag);

    // L2 + means + output gather, one launch
    l2_gemm<<<dim3(8, 1, 6), 256, 0, stream>>>(
        sums3, sumsOvf, counts, W2T, b2f, nodemap, labels, ovfflag,
        d_out, flags);
}